// Round 1
// baseline (183.425 us; speedup 1.0000x reference)
//
#include <hip/hip_runtime.h>
#include <float.h>

#define NA_TOTAL 8400
#define BSZ 32
#define NMAX 64
#define TOPK 9
#define BG_IDX 80

// -------- IoU exactly mirroring the reference formula (no fp contraction) ----
__device__ __forceinline__ float iou_pair(float ax1, float ay1, float ax2, float ay2,
                                          float bx1, float by1, float bx2, float by2) {
#pragma clang fp contract(off)
  float ltx = fmaxf(ax1, bx1);
  float lty = fmaxf(ay1, by1);
  float rbx = fminf(ax2, bx2);
  float rby = fminf(ay2, by2);
  float w = fmaxf(rbx - ltx, 0.0f);
  float h = fmaxf(rby - lty, 0.0f);
  float inter = w * h;
  float a1 = (ax2 - ax1) * (ay2 - ay1);
  float a2 = (bx2 - bx1) * (by2 - by1);
  return inter / (a1 + a2 - inter + 1e-9f);
}

// -------- Stage 1: per (b,g) -> top-9 per level, threshold, set mask bits ----
__global__ __launch_bounds__(256) void stage1_kernel(
    const float* __restrict__ anchors,   // [8400,4]
    const float* __restrict__ gt_boxes,  // [32,64,4]
    const float* __restrict__ mask_gt,   // [32,64]
    unsigned long long* __restrict__ mpos) {  // [32][8400] bitmask over g
#pragma clang fp contract(off)
  const int bg = blockIdx.x;
  const int b = bg >> 6;
  const int g = bg & 63;
  const int tid = threadIdx.x;

  __shared__ float dl[6400];
  __shared__ float rv[256];
  __shared__ int ri[256];
  __shared__ int sel[27];
  __shared__ float selv[27];
  __shared__ float thr_sh;

  float m = mask_gt[bg];
  if (m <= 0.0f) return;  // uniform per block; no barriers crossed

  const float* gtb = gt_boxes + (size_t)bg * 4;
  const float gx1 = gtb[0], gy1 = gtb[1], gx2 = gtb[2], gy2 = gtb[3];
  const float gcx = 0.5f * (gx1 + gx2);
  const float gcy = 0.5f * (gy1 + gy2);

  const int lstart[3] = {0, 6400, 8000};
  const int lsize[3] = {6400, 1600, 400};

  for (int lv = 0; lv < 3; ++lv) {
    const int st = lstart[lv];
    const int na = lsize[lv];
    for (int i = tid; i < na; i += 256) {
      const int a = st + i;
      float ax1 = anchors[a * 4 + 0], ay1 = anchors[a * 4 + 1];
      float ax2 = anchors[a * 4 + 2], ay2 = anchors[a * 4 + 3];
      float acx = 0.5f * (ax1 + ax2);
      float acy = 0.5f * (ay1 + ay2);
      float dx = gcx - acx;
      float dy = gcy - acy;
      dl[i] = sqrtf(dx * dx + dy * dy);
    }
    __syncthreads();
    for (int t = 0; t < TOPK; ++t) {
      float best = FLT_MAX;
      int bi = 0x7fffffff;
      for (int i = tid; i < na; i += 256) {
        float v = dl[i];
        if (v < best || (v == best && i < bi)) { best = v; bi = i; }
      }
      rv[tid] = best;
      ri[tid] = bi;
      __syncthreads();
      for (int s = 128; s > 0; s >>= 1) {
        if (tid < s) {
          float v2 = rv[tid + s];
          int i2 = ri[tid + s];
          if (v2 < rv[tid] || (v2 == rv[tid] && i2 < ri[tid])) {
            rv[tid] = v2;
            ri[tid] = i2;
          }
        }
        __syncthreads();
      }
      if (tid == 0) {
        int w = ri[0];
        sel[lv * TOPK + t] = st + w;
        dl[w] = FLT_MAX;  // exclude from next argmin
      }
      __syncthreads();
    }
  }

  // candidate IoUs (27 candidates, distinct by construction)
  if (tid < 27) {
    int a = sel[tid];
    float ax1 = anchors[a * 4 + 0], ay1 = anchors[a * 4 + 1];
    float ax2 = anchors[a * 4 + 2], ay2 = anchors[a * 4 + 3];
    selv[tid] = iou_pair(gx1, gy1, gx2, gy2, ax1, ay1, ax2, ay2);
  }
  __syncthreads();
  if (tid == 0) {
    double s = 0.0;
    for (int i = 0; i < 27; ++i) s += (double)selv[i];
    double mean = s / 27.0;
    double s2 = 0.0;
    for (int i = 0; i < 27; ++i) {
      double d = (double)selv[i] - mean;
      s2 += d * d;
    }
    thr_sh = (float)(mean + sqrt(s2 / 26.0));  // ddof=1
  }
  __syncthreads();
  if (tid < 27) {
    int a = sel[tid];
    if (selv[tid] > thr_sh) {
      float ax1 = anchors[a * 4 + 0], ay1 = anchors[a * 4 + 1];
      float ax2 = anchors[a * 4 + 2], ay2 = anchors[a * 4 + 3];
      float acx = 0.5f * (ax1 + ax2);
      float acy = 0.5f * (ay1 + ay2);
      float d_in = fminf(fminf(acx - gx1, acy - gy1), fminf(gx2 - acx, gy2 - acy));
      if (d_in > 1e-9f) {
        atomicOr(&mpos[(size_t)b * NA_TOTAL + a], 1ull << g);
      }
    }
  }
}

// -------- Stage 2: per (b,a) -> resolve multi-assignment, write outputs ------
__global__ __launch_bounds__(256) void stage2_kernel(
    const float* __restrict__ anchors,   // [8400,4]
    const float* __restrict__ gt_boxes,  // [32,64,4]
    const int* __restrict__ labels,      // [32,64]
    const float* __restrict__ pred,      // [32,8400,4]
    const unsigned long long* __restrict__ mpos,
    float* __restrict__ out_lab,   // [32,8400]
    float* __restrict__ out_box,   // [32,8400,4]
    float* __restrict__ out_sco,   // [32,8400,80] (pre-zeroed)
    float* __restrict__ out_fgm) { // [32,8400]
#pragma clang fp contract(off)
  const int b = blockIdx.y;
  const int a = blockIdx.x * 256 + threadIdx.x;

  __shared__ float4 gts[64];
  __shared__ int labs[64];
  if (threadIdx.x < 64) {
    gts[threadIdx.x] = ((const float4*)gt_boxes)[b * 64 + threadIdx.x];
    labs[threadIdx.x] = labels[b * 64 + threadIdx.x];
  }
  __syncthreads();
  if (a >= NA_TOTAL) return;

  const size_t idx = (size_t)b * NA_TOTAL + a;
  unsigned long long bits = mpos[idx];
  int fg = __popcll(bits);
  bool pos = fg > 0;
  int target = 0;
  if (fg == 1) {
    target = __builtin_ctzll(bits);
  } else if (fg > 1) {
    // anchor assigned to multiple gts -> argmax_g IoU(gt[g], anchor) (first max)
    float ax1 = anchors[a * 4 + 0], ay1 = anchors[a * 4 + 1];
    float ax2 = anchors[a * 4 + 2], ay2 = anchors[a * 4 + 3];
    float best = -1.0f;
    int bi = 0;
    for (int g2 = 0; g2 < 64; ++g2) {
      float4 gb = gts[g2];
      float v = iou_pair(gb.x, gb.y, gb.z, gb.w, ax1, ay1, ax2, ay2);
      if (v > best) { best = v; bi = g2; }
    }
    target = bi;
  }

  int lab = pos ? labs[target] : BG_IDX;
  out_lab[idx] = (float)lab;
  float4 tb = gts[target];  // background -> gt[0], matching reference
  ((float4*)out_box)[idx] = tb;
  out_fgm[idx] = pos ? 1.0f : 0.0f;
  if (pos) {
    float4 pb = ((const float4*)pred)[idx];
    float im = iou_pair(tb.x, tb.y, tb.z, tb.w, pb.x, pb.y, pb.z, pb.w);
    out_sco[idx * 80 + lab] = im;
  }
}

extern "C" void kernel_launch(void* const* d_in, const int* in_sizes, int n_in,
                              void* d_out, int out_size, void* d_ws, size_t ws_size,
                              hipStream_t stream) {
  const float* anchors = (const float*)d_in[0];
  // d_in[1] = num_anchors_list (compile-time constants here)
  const int* labels = (const int*)d_in[2];
  const float* gt_boxes = (const float*)d_in[3];
  const float* mask_gt = (const float*)d_in[4];
  const float* pred = (const float*)d_in[5];

  float* out = (float*)d_out;
  float* out_lab = out;                                    // 32*8400
  float* out_box = out + (size_t)BSZ * NA_TOTAL;           // 32*8400*4
  float* out_sco = out + (size_t)BSZ * NA_TOTAL * 5;       // 32*8400*80
  float* out_fgm = out + (size_t)BSZ * NA_TOTAL * 85;      // 32*8400

  unsigned long long* mpos = (unsigned long long*)d_ws;

  hipMemsetAsync(mpos, 0, (size_t)BSZ * NA_TOTAL * sizeof(unsigned long long), stream);
  hipMemsetAsync(out_sco, 0, (size_t)BSZ * NA_TOTAL * 80 * sizeof(float), stream);

  stage1_kernel<<<BSZ * NMAX, 256, 0, stream>>>(anchors, gt_boxes, mask_gt, mpos);

  dim3 g2((NA_TOTAL + 255) / 256, BSZ);
  stage2_kernel<<<g2, 256, 0, stream>>>(anchors, gt_boxes, labels, pred, mpos,
                                        out_lab, out_box, out_sco, out_fgm);
}

// Round 2
// 104.920 us; speedup vs baseline: 1.7482x; 1.7482x over previous
//
#include <hip/hip_runtime.h>
#include <float.h>

#define NA_TOTAL 8400
#define BSZ 32
#define NMAX 64
#define BG_IDX 80

// -------- IoU exactly mirroring the reference formula (no fp contraction) ----
__device__ __forceinline__ float iou_pair(float ax1, float ay1, float ax2, float ay2,
                                          float bx1, float by1, float bx2, float by2) {
#pragma clang fp contract(off)
  float ltx = fmaxf(ax1, bx1);
  float lty = fmaxf(ay1, by1);
  float rbx = fminf(ax2, bx2);
  float rby = fminf(ay2, by2);
  float w = fmaxf(rbx - ltx, 0.0f);
  float h = fmaxf(rby - lty, 0.0f);
  float inter = w * h;
  float a1 = (ax2 - ax1) * (ay2 - ay1);
  float a2 = (bx2 - bx1) * (by2 - by1);
  return inter / (a1 + a2 - inter + 1e-9f);
}

// -------- Stage 1: one thread per (b,g). Top-9 per level via 5x5 grid window.
// Proof the window suffices: gt center is within half a cell of the nearest
// grid point, so the 9 points of the 3x3 window are all at dist <= 2.13*s,
// while any point outside the 5x5 window is at dist >= 2.5*s. Strict margin,
// so the true top-9 (with (dist, idx) lexicographic tie-break, == lax.top_k)
// is contained in the 25-candidate window.
__global__ __launch_bounds__(64) void stage1_kernel(
    const float* __restrict__ anchors,   // [8400,4]
    const float* __restrict__ gt_boxes,  // [32,64,4]
    const float* __restrict__ mask_gt,   // [32,64]
    unsigned long long* __restrict__ mpos) {  // [32][8400] bitmask over g
#pragma clang fp contract(off)
  const int tid = threadIdx.x;            // 0..63
  const int t = blockIdx.x * 64 + tid;    // (b,g) flat
  const int b = t >> 6;
  const int g = t & 63;

  // per-thread scratch in LDS (stride 25/27 coprime with 32 banks)
  __shared__ float dl[64 * 25];
  __shared__ float io[64 * 27];
  __shared__ int gidx[64 * 27];

  if (mask_gt[t] <= 0.0f) return;

  const float4 gtb = ((const float4*)gt_boxes)[t];
  const float gx1 = gtb.x, gy1 = gtb.y, gx2 = gtb.z, gy2 = gtb.w;
  const float gcx = 0.5f * (gx1 + gx2);
  const float gcy = 0.5f * (gy1 + gy2);

  int nsel = 0;  // compact write cursor into io/gidx (ends at 27)

#pragma unroll
  for (int lv = 0; lv < 3; ++lv) {
    const int strd = (lv == 0) ? 8 : (lv == 1) ? 16 : 32;
    const int n = (lv == 0) ? 80 : (lv == 1) ? 40 : 20;
    const int startA = (lv == 0) ? 0 : (lv == 1) ? 6400 : 8000;
    const float inv = 1.0f / (float)strd;

    int ix0 = (int)floorf(gcx * inv);
    int iy0 = (int)floorf(gcy * inv);
    ix0 = min(max(ix0, 0), n - 1);
    iy0 = min(max(iy0, 0), n - 1);
    int wx0 = min(max(ix0 - 2, 0), n - 5);
    int wy0 = min(max(iy0 - 2, 0), n - 5);

    // 25 window distances (slot order = increasing linear anchor index)
    for (int wy = 0; wy < 5; ++wy) {
      for (int wx = 0; wx < 5; ++wx) {
        int a = startA + (iy0 * 0 + wy0 + wy) * n + (wx0 + wx);
        float4 ab = ((const float4*)anchors)[a];
        float acx = 0.5f * (ab.x + ab.z);
        float acy = 0.5f * (ab.y + ab.w);
        float dx = gcx - acx;
        float dy = gcy - acy;
        dl[tid * 25 + wy * 5 + wx] = sqrtf(dx * dx + dy * dy);
      }
    }

    // rank each slot: # of slots strictly better under (dist, idx) lex order
    unsigned selm = 0;
    for (int i = 0; i < 25; ++i) {
      float di = dl[tid * 25 + i];
      int cnt = 0;
      for (int j = 0; j < 25; ++j) {
        float dj = dl[tid * 25 + j];
        cnt += (dj < di) || (dj == di && j < i);
      }
      if (cnt < 9) selm |= (1u << i);
    }

    // IoU of the 9 selected candidates
    for (int i = 0; i < 25; ++i) {
      if ((selm >> i) & 1u) {
        int a = startA + (wy0 + i / 5) * n + (wx0 + i % 5);
        float4 ab = ((const float4*)anchors)[a];
        float v = iou_pair(gx1, gy1, gx2, gy2, ab.x, ab.y, ab.z, ab.w);
        io[tid * 27 + nsel] = v;
        gidx[tid * 27 + nsel] = a;
        ++nsel;
      }
    }
  }

  // thr = mean + std (ddof=1), double accumulation, two-pass (matches passing v1)
  double s = 0.0;
  for (int k = 0; k < 27; ++k) s += (double)io[tid * 27 + k];
  double mean = s / 27.0;
  double s2 = 0.0;
  for (int k = 0; k < 27; ++k) {
    double d = (double)io[tid * 27 + k] - mean;
    s2 += d * d;
  }
  float thr = (float)(mean + sqrt(s2 / 26.0));

  for (int k = 0; k < 27; ++k) {
    float v = io[tid * 27 + k];
    if (v > thr) {
      int a = gidx[tid * 27 + k];
      float4 ab = ((const float4*)anchors)[a];
      float acx = 0.5f * (ab.x + ab.z);
      float acy = 0.5f * (ab.y + ab.w);
      float d_in = fminf(fminf(acx - gx1, acy - gy1), fminf(gx2 - acx, gy2 - acy));
      if (d_in > 1e-9f) {
        atomicOr(&mpos[(size_t)b * NA_TOTAL + a], 1ull << g);
      }
    }
  }
}

// -------- Stage 2: per (b,a) -> resolve multi-assignment, write all but scores
__global__ __launch_bounds__(256) void stage2_kernel(
    const float* __restrict__ anchors,   // [8400,4]
    const float* __restrict__ gt_boxes,  // [32,64,4]
    const int* __restrict__ labels,      // [32,64]
    const float* __restrict__ pred,      // [32,8400,4]
    const unsigned long long* __restrict__ mpos,
    float* __restrict__ out_lab,   // [32,8400]
    float* __restrict__ out_box,   // [32,8400,4]
    float* __restrict__ out_fgm,   // [32,8400]
    float* __restrict__ im_ws) {   // [32,8400] iou_max stash for stage 3
#pragma clang fp contract(off)
  const int b = blockIdx.y;
  const int a = blockIdx.x * 256 + threadIdx.x;

  __shared__ float4 gts[64];
  __shared__ int labs[64];
  if (threadIdx.x < 64) {
    gts[threadIdx.x] = ((const float4*)gt_boxes)[b * 64 + threadIdx.x];
    labs[threadIdx.x] = labels[b * 64 + threadIdx.x];
  }
  __syncthreads();
  if (a >= NA_TOTAL) return;

  const size_t idx = (size_t)b * NA_TOTAL + a;
  unsigned long long bits = mpos[idx];
  int fg = __popcll(bits);
  bool pos = fg > 0;
  int target = 0;
  if (fg == 1) {
    target = __builtin_ctzll(bits);
  } else if (fg > 1) {
    // anchor assigned to multiple gts -> argmax_g IoU(gt[g], anchor) (first max)
    float ax1 = anchors[a * 4 + 0], ay1 = anchors[a * 4 + 1];
    float ax2 = anchors[a * 4 + 2], ay2 = anchors[a * 4 + 3];
    float best = -1.0f;
    int bi = 0;
    for (int g2 = 0; g2 < 64; ++g2) {
      float4 gb = gts[g2];
      float v = iou_pair(gb.x, gb.y, gb.z, gb.w, ax1, ay1, ax2, ay2);
      if (v > best) { best = v; bi = g2; }
    }
    target = bi;
  }

  int lab = pos ? labs[target] : BG_IDX;
  out_lab[idx] = (float)lab;
  float4 tb = gts[target];  // background -> gt[0], matching reference
  ((float4*)out_box)[idx] = tb;
  out_fgm[idx] = pos ? 1.0f : 0.0f;
  float im = 0.0f;
  if (pos) {
    float4 pb = ((const float4*)pred)[idx];
    im = iou_pair(tb.x, tb.y, tb.z, tb.w, pb.x, pb.y, pb.z, pb.w);
  }
  im_ws[idx] = im;
}

// -------- Stage 3: fully-coalesced one-shot score write (replaces 86MB memset)
__global__ __launch_bounds__(256) void stage3_kernel(
    const float* __restrict__ out_lab,  // [32*8400] (written by stage 2)
    const float* __restrict__ im_ws,    // [32*8400]
    float4* __restrict__ out_sco4) {    // [32*8400*20] float4 view of scores
  const int u = blockIdx.x * 256 + threadIdx.x;  // float4 index
  const int total = BSZ * NA_TOTAL * 20;
  if (u >= total) return;
  const int anch = u / 20;
  const int q = u - anch * 20;  // which float4 of the 80-score row
  const int lab = (int)out_lab[anch];
  const float im = im_ws[anch];
  const int c0 = q * 4;
  float4 v;
  v.x = (lab == c0 + 0) ? im : 0.0f;
  v.y = (lab == c0 + 1) ? im : 0.0f;
  v.z = (lab == c0 + 2) ? im : 0.0f;
  v.w = (lab == c0 + 3) ? im : 0.0f;
  out_sco4[u] = v;
}

extern "C" void kernel_launch(void* const* d_in, const int* in_sizes, int n_in,
                              void* d_out, int out_size, void* d_ws, size_t ws_size,
                              hipStream_t stream) {
  const float* anchors = (const float*)d_in[0];
  // d_in[1] = num_anchors_list (compile-time constants here)
  const int* labels = (const int*)d_in[2];
  const float* gt_boxes = (const float*)d_in[3];
  const float* mask_gt = (const float*)d_in[4];
  const float* pred = (const float*)d_in[5];

  float* out = (float*)d_out;
  float* out_lab = out;                                    // 32*8400
  float* out_box = out + (size_t)BSZ * NA_TOTAL;           // 32*8400*4
  float* out_sco = out + (size_t)BSZ * NA_TOTAL * 5;       // 32*8400*80
  float* out_fgm = out + (size_t)BSZ * NA_TOTAL * 85;      // 32*8400

  unsigned long long* mpos = (unsigned long long*)d_ws;    // 2.15 MB
  float* im_ws = (float*)(mpos + (size_t)BSZ * NA_TOTAL);  // +1.07 MB

  hipMemsetAsync(mpos, 0, (size_t)BSZ * NA_TOTAL * sizeof(unsigned long long), stream);

  stage1_kernel<<<(BSZ * NMAX) / 64, 64, 0, stream>>>(anchors, gt_boxes, mask_gt, mpos);

  dim3 g2((NA_TOTAL + 255) / 256, BSZ);
  stage2_kernel<<<g2, 256, 0, stream>>>(anchors, gt_boxes, labels, pred, mpos,
                                        out_lab, out_box, out_fgm, im_ws);

  const int total4 = BSZ * NA_TOTAL * 20;
  stage3_kernel<<<(total4 + 255) / 256, 256, 0, stream>>>(out_lab, im_ws,
                                                          (float4*)out_sco);
}